// Round 7
// baseline (184.465 us; speedup 1.0000x reference)
//
#include <hip/hip_runtime.h>

#define BN_EPS 1e-5f

constexpr int PN0 = 262144, PN1 = 65536, PN2 = 16384, PN3 = 4096;
constexpr size_t MB = 1u << 20;

typedef __attribute__((ext_vector_type(8))) short short8;
typedef __attribute__((ext_vector_type(4))) float f32x4;
typedef __attribute__((ext_vector_type(4))) unsigned int u32x4;

typedef const __attribute__((address_space(1))) unsigned int gu32;
typedef __attribute__((address_space(3))) unsigned int lu32;

__device__ __forceinline__ unsigned f2bf(float f) {
    unsigned u = __builtin_bit_cast(unsigned, f);
    u += 0x7fff + ((u >> 16) & 1);
    return u >> 16;
}
__device__ __forceinline__ float bf2f(unsigned h) {
    return __builtin_bit_cast(float, h << 16);
}
__device__ __forceinline__ f32x4 ntload4(const float* p) {
    return __builtin_nontemporal_load(reinterpret_cast<const f32x4*>(p));
}
__device__ __forceinline__ void ntstore4(float* p, f32x4 v) {
    __builtin_nontemporal_store(v, reinterpret_cast<f32x4*>(p));
}

// ---------------- fused histogram of all three gather-index arrays ----------------
__global__ __launch_bounds__(256) void hist_all(const int* __restrict__ idx0,
                                                const int* __restrict__ idx1,
                                                const int* __restrict__ idx2,
                                                int* __restrict__ cnt3,
                                                int* __restrict__ cnt2,
                                                int* __restrict__ cnt1) {
    int i = blockIdx.x * 256 + threadIdx.x;
    if (blockIdx.y == 0) {
        if (i < PN2) atomicAdd(&cnt3[idx0[i]], 1);
    } else if (blockIdx.y == 1) {
        if (i < PN1) atomicAdd(&cnt2[idx1[i]], 1);
    } else {
        atomicAdd(&cnt1[idx2[i]], 1);
    }
}

// ---------------- weighted per-channel stats over f3 (+convert to bf16) ----------------
template<int C>
__global__ __launch_bounds__(256) void stats_f3(const float* __restrict__ src,
                                                const int* __restrict__ cnt,
                                                float* __restrict__ part,
                                                unsigned short* __restrict__ cvt_out) {
    constexpr int G = C / 8;
    constexpr int NL = 256 / G;
    __shared__ float red[NL][G][8];
    const int tid = threadIdx.x;
    const int cg = tid % G;
    const int lr = tid / G;
    const int r0 = blockIdx.x * (NL * 4);
    float s[8] = {}, q[8] = {};
    #pragma unroll
    for (int i = 0; i < 4; ++i) {
        int r = r0 + lr + NL * i;
        float w = (float)cnt[r];
        const float* p = src + (size_t)r * C + cg * 8;
        float4 a = *reinterpret_cast<const float4*>(p);
        float4 b = *reinterpret_cast<const float4*>(p + 4);
        float v[8] = {a.x, a.y, a.z, a.w, b.x, b.y, b.z, b.w};
        uint4 o;
        o.x = f2bf(v[0]) | (f2bf(v[1]) << 16);
        o.y = f2bf(v[2]) | (f2bf(v[3]) << 16);
        o.z = f2bf(v[4]) | (f2bf(v[5]) << 16);
        o.w = f2bf(v[6]) | (f2bf(v[7]) << 16);
        *reinterpret_cast<uint4*>(cvt_out + (size_t)r * C + cg * 8) = o;
        #pragma unroll
        for (int j = 0; j < 8; ++j) { s[j] += w * v[j]; q[j] += w * v[j] * v[j]; }
    }
    #pragma unroll
    for (int j = 0; j < 8; ++j) red[lr][cg][j] = s[j];
    __syncthreads();
    if (tid < G) {
        float ss[8] = {};
        #pragma unroll
        for (int l = 0; l < NL; ++l)
            #pragma unroll
            for (int j = 0; j < 8; ++j) ss[j] += red[l][tid][j];
        #pragma unroll
        for (int j = 0; j < 8; ++j)
            part[((size_t)blockIdx.x * C + tid * 8 + j) * 2] = ss[j];
    }
    __syncthreads();
    #pragma unroll
    for (int j = 0; j < 8; ++j) red[lr][cg][j] = q[j];
    __syncthreads();
    if (tid < G) {
        float qq[8] = {};
        #pragma unroll
        for (int l = 0; l < NL; ++l)
            #pragma unroll
            for (int j = 0; j < 8; ++j) qq[j] += red[l][tid][j];
        #pragma unroll
        for (int j = 0; j < 8; ++j)
            part[((size_t)blockIdx.x * C + tid * 8 + j) * 2 + 1] = qq[j];
    }
}

// ---------------- fused redfin + prescale: part -> (scale,shift in LDS) -> W',d ----------------
// Wp layout: [colblock=n/64][ (n64*K + k) ^ ((n64&7)<<3) ]  (ushort units)
template<int K, int COUT, int NB>
__global__ __launch_bounds__(256) void prep(const float* __restrict__ part,
                                            const float* __restrict__ bnw,
                                            const float* __restrict__ bnb,
                                            float invN,
                                            const float* __restrict__ W,
                                            unsigned short* __restrict__ Wp,
                                            float* __restrict__ d) {
    __shared__ float sc[K], sh[K];
    const int tid = threadIdx.x;
    // phase 1: reduce partials -> scale/shift (redundant per block; blocks are few)
    for (int c = tid; c < K; c += 256) {
        float s = 0.f, q = 0.f;
        for (int b = 0; b < NB; ++b) {
            float2 p = *reinterpret_cast<const float2*>(part + ((size_t)b * K + c) * 2);
            s += p.x;
            q += p.y;
        }
        float mean = s * invN;
        float var = fmaxf(q * invN - mean * mean, 0.f);
        float scl = bnw[c] * rsqrtf(var + BN_EPS);
        sc[c] = scl;
        sh[c] = bnb[c] - mean * scl;
    }
    __syncthreads();
    // phase 2: prescale 16 W rows per block
    const int nl = tid >> 4;
    const int kc = tid & 15;
    const int n = blockIdx.x * 16 + nl;
    const int cb = n >> 6, n64 = n & 63;
    const float* wrow = W + (size_t)n * K;
    unsigned short* wp = Wp + (size_t)cb * 64 * K;
    float dp = 0.f;
    #pragma unroll
    for (int i = 0; i < K / 128; ++i) {
        int k = kc * 8 + i * 128;
        float4 w0 = *reinterpret_cast<const float4*>(wrow + k);
        float4 w1 = *reinterpret_cast<const float4*>(wrow + k + 4);
        float4 s0 = *reinterpret_cast<const float4*>(&sc[k]);
        float4 s1 = *reinterpret_cast<const float4*>(&sc[k + 4]);
        float4 h0 = *reinterpret_cast<const float4*>(&sh[k]);
        float4 h1 = *reinterpret_cast<const float4*>(&sh[k + 4]);
        dp += h0.x * w0.x + h0.y * w0.y + h0.z * w0.z + h0.w * w0.w
            + h1.x * w1.x + h1.y * w1.y + h1.z * w1.z + h1.w * w1.w;
        uint4 o;
        o.x = f2bf(w0.x * s0.x) | (f2bf(w0.y * s0.y) << 16);
        o.y = f2bf(w0.z * s0.z) | (f2bf(w0.w * s0.w) << 16);
        o.z = f2bf(w1.x * s1.x) | (f2bf(w1.y * s1.y) << 16);
        o.w = f2bf(w1.z * s1.z) | (f2bf(w1.w * s1.w) << 16);
        int si = (n64 * K + k) ^ ((n64 & 7) << 3);
        *reinterpret_cast<uint4*>(wp + si) = o;
    }
    dp += __shfl_xor(dp, 1); dp += __shfl_xor(dp, 2);
    dp += __shfl_xor(dp, 4); dp += __shfl_xor(dp, 8);
    if (kc == 0) d[n] = dp;
}

// ---------------- dense one-shot GEMM over the coarse level ----------------
template<int K, int C, int WAVES>
__global__ __launch_bounds__(WAVES * 64, 4)
void gemm_dense(const unsigned short* __restrict__ src,
                const unsigned short* __restrict__ Wp,
                const float* __restrict__ dvec,
                unsigned short* __restrict__ dec) {
    constexpr int KK = K / 32;
    constexpr int CH = K / 8;
    __shared__ unsigned short Wl[64 * K];

    const int tid = threadIdx.x;
    const int lane = tid & 63;
    const int wv = tid >> 6;
    const int l15 = lane & 15, lg = lane >> 4;
    const int ncol0 = blockIdx.y * 64;
    const int chunk = blockIdx.x * WAVES + wv;

    {
        const char* g = (const char*)(Wp + (size_t)blockIdx.y * 64 * K);
        char* l = (char*)Wl;
        #pragma unroll
        for (int i = 0; i < CH / WAVES; ++i) {
            int ch = i * WAVES + wv;
            __builtin_amdgcn_global_load_lds((gu32*)(g + ch * 1024 + lane * 16),
                                             (lu32*)(l + ch * 1024 + lane * 16), 16, 0, 0);
        }
    }

    const unsigned short* xp = src + (size_t)(chunk * 16 + l15) * K + lg * 8;
    short8 xf[KK];
    #pragma unroll
    for (int kk = 0; kk < KK; ++kk)
        xf[kk] = *reinterpret_cast<const short8*>(xp + kk * 32);

    float4 dr[4];
    #pragma unroll
    for (int ni = 0; ni < 4; ++ni)
        dr[ni] = *reinterpret_cast<const float4*>(&dvec[ncol0 + ni * 16 + lg * 4]);

    __syncthreads();

    f32x4 acc[4];
    #pragma unroll
    for (int ni = 0; ni < 4; ++ni) acc[ni] = (f32x4){0.f, 0.f, 0.f, 0.f};
    #pragma unroll
    for (int kk = 0; kk < KK; ++kk) {
        #pragma unroll
        for (int ni = 0; ni < 4; ++ni) {
            const int si = ((ni * 16 + l15) * K + kk * 32 + lg * 8) ^ ((l15 & 7) << 3);
            short8 wf = *reinterpret_cast<const short8*>(&Wl[si]);
            acc[ni] = __builtin_amdgcn_mfma_f32_16x16x32_bf16(wf, xf[kk], acc[ni], 0, 0, 0);
        }
    }

    const size_t rowoff = (size_t)(chunk * 16 + l15) * C + ncol0;
    #pragma unroll
    for (int ni = 0; ni < 4; ++ni) {
        size_t off = rowoff + ni * 16 + lg * 4;
        float v0 = dr[ni].x + acc[ni][0];
        float v1 = dr[ni].y + acc[ni][1];
        float v2 = dr[ni].z + acc[ni][2];
        float v3 = dr[ni].w + acc[ni][3];
        *reinterpret_cast<uint2*>(&dec[off]) =
            make_uint2(f2bf(v0) | (f2bf(v1) << 16), f2bf(v2) | (f2bf(v3) << 16));
    }
}

// ---------------- batched-MLP gather-add (+ optional fused weighted stats) ----------------
// out[r][c] = base[r][c] + dec[idx[r]][c]. All loads issued as independent
// batches (forces high VMEM concurrency); NT hints keep L2 for dec.
template<int C, int IT, bool STATS, bool OUT_F32>
__global__ __launch_bounds__(256, 3) void ga_v2(const float* __restrict__ base,
                                                const unsigned short* __restrict__ dec,
                                                const int* __restrict__ idx,
                                                const int* __restrict__ cnt_next,
                                                void* __restrict__ outv,
                                                float* __restrict__ part) {
    constexpr int G = C / 8;
    constexpr int NL = 256 / G;
    __shared__ float red[STATS ? NL * G * 8 : 1];
    const int tid = threadIdx.x;
    const int cg = tid % G;
    const int lr = tid / G;
    const int r0 = blockIdx.x * (NL * IT);

    int g[IT];
    #pragma unroll
    for (int i = 0; i < IT; ++i) g[i] = idx[r0 + lr + NL * i];

    float wreg[IT];
    if constexpr (STATS) {
        #pragma unroll
        for (int i = 0; i < IT; ++i) wreg[i] = (float)cnt_next[r0 + lr + NL * i];
    }

    u32x4 dv[IT];
    #pragma unroll
    for (int i = 0; i < IT; ++i)
        dv[i] = *reinterpret_cast<const u32x4*>(dec + (size_t)g[i] * C + cg * 8);

    f32x4 b0[IT], b1[IT];
    #pragma unroll
    for (int i = 0; i < IT; ++i) {
        const float* bp = base + (size_t)(r0 + lr + NL * i) * C + cg * 8;
        b0[i] = ntload4(bp);
        b1[i] = ntload4(bp + 4);
    }

    float s[8] = {}, q[8] = {};
    #pragma unroll
    for (int i = 0; i < IT; ++i) {
        const int r = r0 + lr + NL * i;
        float v[8];
        v[0] = b0[i][0] + bf2f(dv[i][0] & 0xffffu);
        v[1] = b0[i][1] + bf2f(dv[i][0] >> 16);
        v[2] = b0[i][2] + bf2f(dv[i][1] & 0xffffu);
        v[3] = b0[i][3] + bf2f(dv[i][1] >> 16);
        v[4] = b1[i][0] + bf2f(dv[i][2] & 0xffffu);
        v[5] = b1[i][1] + bf2f(dv[i][2] >> 16);
        v[6] = b1[i][2] + bf2f(dv[i][3] & 0xffffu);
        v[7] = b1[i][3] + bf2f(dv[i][3] >> 16);
        if constexpr (OUT_F32) {
            float* op = (float*)outv + (size_t)r * C + cg * 8;
            ntstore4(op, (f32x4){v[0], v[1], v[2], v[3]});
            ntstore4(op + 4, (f32x4){v[4], v[5], v[6], v[7]});
        } else {
            unsigned h[8];
            #pragma unroll
            for (int j = 0; j < 8; ++j) h[j] = f2bf(v[j]);
            u32x4 o = {h[0] | (h[1] << 16), h[2] | (h[3] << 16),
                       h[4] | (h[5] << 16), h[6] | (h[7] << 16)};
            *reinterpret_cast<u32x4*>((unsigned short*)outv + (size_t)r * C + cg * 8) = o;
            if constexpr (STATS) {
                #pragma unroll
                for (int j = 0; j < 8; ++j) {
                    float rv = bf2f(h[j]);
                    s[j] += wreg[i] * rv;
                    q[j] += wreg[i] * rv * rv;
                }
            }
        }
    }

    if constexpr (STATS) {
        #pragma unroll
        for (int j = 0; j < 8; ++j) red[(lr * G + cg) * 8 + j] = s[j];
        __syncthreads();
        if (tid < G) {
            float ss[8] = {};
            #pragma unroll
            for (int l = 0; l < NL; ++l)
                #pragma unroll
                for (int j = 0; j < 8; ++j) ss[j] += red[(l * G + tid) * 8 + j];
            #pragma unroll
            for (int j = 0; j < 8; ++j)
                part[((size_t)blockIdx.x * C + tid * 8 + j) * 2] = ss[j];
        }
        __syncthreads();
        #pragma unroll
        for (int j = 0; j < 8; ++j) red[(lr * G + cg) * 8 + j] = q[j];
        __syncthreads();
        if (tid < G) {
            float qq[8] = {};
            #pragma unroll
            for (int l = 0; l < NL; ++l)
                #pragma unroll
                for (int j = 0; j < 8; ++j) qq[j] += red[(l * G + tid) * 8 + j];
            #pragma unroll
            for (int j = 0; j < 8; ++j)
                part[((size_t)blockIdx.x * C + tid * 8 + j) * 2 + 1] = qq[j];
        }
    }
}

extern "C" void kernel_launch(void* const* d_in, const int* in_sizes, int n_in,
                              void* d_out, int out_size, void* d_ws, size_t ws_size,
                              hipStream_t stream) {
    const float* f0    = (const float*)d_in[0];
    const float* f1    = (const float*)d_in[1];
    const float* f2    = (const float*)d_in[2];
    const float* f3    = (const float*)d_in[3];
    const float* bn_w2 = (const float*)d_in[4];
    const float* bn_b2 = (const float*)d_in[5];
    const float* W2    = (const float*)d_in[6];
    const float* bn_w1 = (const float*)d_in[7];
    const float* bn_b1 = (const float*)d_in[8];
    const float* W1    = (const float*)d_in[9];
    const float* bn_w0 = (const float*)d_in[10];
    const float* bn_b0 = (const float*)d_in[11];
    const float* W0    = (const float*)d_in[12];
    const int*   idx0  = (const int*)d_in[13];
    const int*   idx1  = (const int*)d_in[14];
    const int*   idx2  = (const int*)d_in[15];
    float* out = (float*)d_out;

    // ---- workspace layout (no aliasing) ----
    char* wsb = (char*)d_ws;
    unsigned short* f3bf = (unsigned short*)wsb;              // [0,4MB)
    unsigned short* dec2 = (unsigned short*)(wsb + 4 * MB);   // 2MB
    unsigned short* dec1 = (unsigned short*)(wsb + 6 * MB);   // 4MB
    unsigned short* dec0 = (unsigned short*)(wsb + 10 * MB);  // 8MB
    unsigned short* f2p  = (unsigned short*)(wsb + 18 * MB);  // 8MB
    unsigned short* f1p  = (unsigned short*)(wsb + 26 * MB);  // 16MB
    unsigned short* Wp2  = (unsigned short*)(wsb + 42 * MB);  // 256KB
    unsigned short* Wp1  = Wp2 + 4 * 64 * 512;                // 64KB
    unsigned short* Wp0  = Wp1 + 2 * 64 * 256;                // 16KB
    int* cnt3 = (int*)(Wp0 + 64 * 128);                       // zero region start
    int* cnt2 = cnt3 + PN3;
    int* cnt1 = cnt2 + PN2;                                   // zero region end
    float* part2 = (float*)(cnt1 + PN1);                      // 256*512*2  = 1MB
    float* part1 = part2 + 256 * 512 * 2;                     // 512*256*2  = 1MB
    float* part0 = part1 + 512 * 256 * 2;                     // 1024*128*2 = 1MB
    float* d2 = part0 + 1024 * 128 * 2;                       // 256
    float* d1 = d2 + 256;                                     // 128
    float* d0 = d1 + 128;                                     // 64

    hipMemsetAsync(cnt3, 0, (size_t)(PN3 + PN2 + PN1) * sizeof(int), stream);
    hist_all<<<dim3(PN0 / 256, 3), 256, 0, stream>>>(idx0, idx1, idx2, cnt3, cnt2, cnt1);

    // ---- level 2 ----
    stats_f3<512><<<256, 256, 0, stream>>>(f3, cnt3, part2, f3bf);
    prep<512, 256, 256><<<16, 256, 0, stream>>>(part2, bn_w2, bn_b2, 1.f / PN2, W2, Wp2, d2);
    gemm_dense<512, 256, 4><<<dim3(PN3 / 64, 4), 256, 0, stream>>>(f3bf, Wp2, d2, dec2);
    ga_v2<256, 4, true, false><<<PN2 / 32, 256, 0, stream>>>(f2, dec2, idx0, cnt2, f2p, part1);

    // ---- level 1 ----
    prep<256, 128, 512><<<8, 256, 0, stream>>>(part1, bn_w1, bn_b1, 1.f / PN1, W1, Wp1, d1);
    gemm_dense<256, 128, 4><<<dim3(PN2 / 64, 2), 256, 0, stream>>>(f2p, Wp1, d1, dec1);
    ga_v2<128, 4, true, false><<<PN1 / 64, 256, 0, stream>>>(f1, dec1, idx1, cnt1, f1p, part0);

    // ---- level 0 ----
    prep<128, 64, 1024><<<4, 256, 0, stream>>>(part0, bn_w0, bn_b0, 1.f / PN0, W0, Wp0, d0);
    gemm_dense<128, 64, 4><<<dim3(PN1 / 64, 1), 256, 0, stream>>>(f1p, Wp0, d0, dec0);
    ga_v2<64, 8, false, true><<<PN0 / 256, 256, 0, stream>>>(f0, dec0, idx2, nullptr, out, nullptr);
}

// Round 9
// 168.015 us; speedup vs baseline: 1.0979x; 1.0979x over previous
//
#include <hip/hip_runtime.h>
#include <hip/hip_cooperative_groups.h>

namespace cg = cooperative_groups;

#define BN_EPS 1e-5f

constexpr int PN0 = 262144, PN1 = 65536, PN2 = 16384, PN3 = 4096;
constexpr int NBLK = 256, NTHR = 256;
constexpr size_t MB = 1u << 20;

typedef __attribute__((ext_vector_type(8))) short short8;
typedef __attribute__((ext_vector_type(4))) float f32x4;
typedef __attribute__((ext_vector_type(4))) unsigned int u32x4;

typedef const __attribute__((address_space(1))) unsigned int gu32;
typedef __attribute__((address_space(3))) unsigned int lu32;

__device__ __forceinline__ unsigned f2bf(float f) {
    unsigned u = __builtin_bit_cast(unsigned, f);
    u += 0x7fff + ((u >> 16) & 1);
    return u >> 16;
}
__device__ __forceinline__ float bf2f(unsigned h) {
    return __builtin_bit_cast(float, h << 16);
}
__device__ __forceinline__ f32x4 ntload4(const float* p) {
    return __builtin_nontemporal_load(reinterpret_cast<const f32x4*>(p));
}
__device__ __forceinline__ void ntstore4(float* p, f32x4 v) {
    __builtin_nontemporal_store(v, reinterpret_cast<f32x4*>(p));
}

struct MegaArgs {
    const float *f0, *f1, *f2, *f3;
    const float *bnw2, *bnb2, *W2;
    const float *bnw1, *bnb1, *W1;
    const float *bnw0, *bnb0, *W0;
    const int *idx0, *idx1, *idx2;
    unsigned short *f3bf, *dec2, *dec1, *dec0, *f2p, *f1p, *Wp2, *Wp1, *Wp0;
    int *cnt3, *cnt2, *cnt1;
    float *part2, *part1, *part0;
    float *d2, *d1, *d0;
    float *out;
};

// ---- block-level tree reduce of s/q[8] per (lr,cg) into part[vb] ----
template<int G, int NL>
__device__ __forceinline__ void red_write(float* aux, const float s[8], const float q[8],
                                          int tid, int lr, int cgi,
                                          float* part, int vb, int C) {
    #pragma unroll
    for (int j = 0; j < 8; ++j) aux[(lr * G + cgi) * 8 + j] = s[j];
    __syncthreads();
    if (tid < G) {
        float ss[8] = {};
        for (int l = 0; l < NL; ++l)
            #pragma unroll
            for (int j = 0; j < 8; ++j) ss[j] += aux[(l * G + tid) * 8 + j];
        #pragma unroll
        for (int j = 0; j < 8; ++j)
            part[((size_t)vb * C + tid * 8 + j) * 2] = ss[j];
    }
    __syncthreads();
    #pragma unroll
    for (int j = 0; j < 8; ++j) aux[(lr * G + cgi) * 8 + j] = q[j];
    __syncthreads();
    if (tid < G) {
        float qq[8] = {};
        for (int l = 0; l < NL; ++l)
            #pragma unroll
            for (int j = 0; j < 8; ++j) qq[j] += aux[(l * G + tid) * 8 + j];
        #pragma unroll
        for (int j = 0; j < 8; ++j)
            part[((size_t)vb * C + tid * 8 + j) * 2 + 1] = qq[j];
    }
    __syncthreads();  // aux reusable immediately after return
}

// ---- P1: hist idx0 (blocks 0..63) || hist idx1 (blocks 64..255) ----
__device__ void phase_hist(const MegaArgs& a, int bid, int tid) {
    if (bid < 64) {
        atomicAdd(&a.cnt3[a.idx0[bid * NTHR + tid]], 1);
    } else {
        int t = (bid - 64) * NTHR + tid;           // 0..49151
        atomicAdd(&a.cnt2[a.idx1[t]], 1);
        int t2 = t + 49152;
        if (t2 < PN1) atomicAdd(&a.cnt2[a.idx1[t2]], 1);
    }
}

// ---- P2: weighted stats over f3 + f3->bf16 (blocks 0..127) || hist idx2 (128..255) ----
__device__ void phase_stats(const MegaArgs& a, int bid, int tid, float* aux) {
    if (bid < 128) {
        const int cgi = tid & 63, lr = tid >> 6;
        const int r0 = bid * 32;
        float s[8] = {}, q[8] = {};
        #pragma unroll
        for (int i = 0; i < 8; ++i) {
            int r = r0 + lr + 4 * i;
            float w = (float)a.cnt3[r];
            const float* p = a.f3 + (size_t)r * 512 + cgi * 8;
            float4 x0 = *reinterpret_cast<const float4*>(p);
            float4 x1 = *reinterpret_cast<const float4*>(p + 4);
            float v[8] = {x0.x, x0.y, x0.z, x0.w, x1.x, x1.y, x1.z, x1.w};
            uint4 o;
            o.x = f2bf(v[0]) | (f2bf(v[1]) << 16);
            o.y = f2bf(v[2]) | (f2bf(v[3]) << 16);
            o.z = f2bf(v[4]) | (f2bf(v[5]) << 16);
            o.w = f2bf(v[6]) | (f2bf(v[7]) << 16);
            *reinterpret_cast<uint4*>(a.f3bf + (size_t)r * 512 + cgi * 8) = o;
            #pragma unroll
            for (int j = 0; j < 8; ++j) { s[j] += w * v[j]; q[j] += w * v[j] * v[j]; }
        }
        red_write<64, 4>(aux, s, q, tid, lr, cgi, a.part2, bid, 512);
    } else {
        int base = (bid - 128) * 2048;
        #pragma unroll
        for (int i = 0; i < 8; ++i)
            atomicAdd(&a.cnt1[a.idx2[base + i * NTHR + tid]], 1);
    }
}

// ---- fused redfin + W prescale (pre-swizzled bf16 W' + d) ----
template<int K, int NB>
__device__ void prep_phase(int bid, int tid, const float* part,
                           const float* bnw, const float* bnb, float invN,
                           const float* W, unsigned short* Wp, float* d,
                           float* aux) {
    float* sc = aux;
    float* sh = aux + K;
    for (int c = tid; c < K; c += NTHR) {
        float s = 0.f, q = 0.f;
        for (int b = 0; b < NB; ++b) {
            float2 p = *reinterpret_cast<const float2*>(part + ((size_t)b * K + c) * 2);
            s += p.x;
            q += p.y;
        }
        float mean = s * invN;
        float var = fmaxf(q * invN - mean * mean, 0.f);
        float scl = bnw[c] * rsqrtf(var + BN_EPS);
        sc[c] = scl;
        sh[c] = bnb[c] - mean * scl;
    }
    __syncthreads();
    const int nl = tid >> 4;
    const int kc = tid & 15;
    const int n = bid * 16 + nl;
    const int cb = n >> 6, n64 = n & 63;
    const float* wrow = W + (size_t)n * K;
    unsigned short* wp = Wp + (size_t)cb * 64 * K;
    float dp = 0.f;
    #pragma unroll
    for (int i = 0; i < K / 128; ++i) {
        int k = kc * 8 + i * 128;
        float4 w0 = *reinterpret_cast<const float4*>(wrow + k);
        float4 w1 = *reinterpret_cast<const float4*>(wrow + k + 4);
        float4 s0 = *reinterpret_cast<const float4*>(&sc[k]);
        float4 s1 = *reinterpret_cast<const float4*>(&sc[k + 4]);
        float4 h0 = *reinterpret_cast<const float4*>(&sh[k]);
        float4 h1 = *reinterpret_cast<const float4*>(&sh[k + 4]);
        dp += h0.x * w0.x + h0.y * w0.y + h0.z * w0.z + h0.w * w0.w
            + h1.x * w1.x + h1.y * w1.y + h1.z * w1.z + h1.w * w1.w;
        uint4 o;
        o.x = f2bf(w0.x * s0.x) | (f2bf(w0.y * s0.y) << 16);
        o.y = f2bf(w0.z * s0.z) | (f2bf(w0.w * s0.w) << 16);
        o.z = f2bf(w1.x * s1.x) | (f2bf(w1.y * s1.y) << 16);
        o.w = f2bf(w1.z * s1.z) | (f2bf(w1.w * s1.w) << 16);
        int si = (n64 * K + k) ^ ((n64 & 7) << 3);
        *reinterpret_cast<uint4*>(wp + si) = o;
    }
    dp += __shfl_xor(dp, 1); dp += __shfl_xor(dp, 2);
    dp += __shfl_xor(dp, 4); dp += __shfl_xor(dp, 8);
    if (kc == 0) d[n] = dp;
}

// ---- dense GEMM, one (chunk, panel): DMA W' -> LDS, MFMA, store dec ----
template<int K, int C>
__device__ void gemm_one(int chunk, int panel, int tid,
                         const unsigned short* src, const unsigned short* Wp,
                         const float* dvec, unsigned short* dec,
                         unsigned short* Wl) {
    constexpr int KK = K / 32;
    constexpr int CH = K / 8;
    const int lane = tid & 63;
    const int wv = tid >> 6;
    const int l15 = lane & 15, lg = lane >> 4;
    const int ncol0 = panel * 64;

    {
        const char* g = (const char*)(Wp + (size_t)panel * 64 * K);
        char* l = (char*)Wl;
        #pragma unroll
        for (int i = 0; i < CH / 4; ++i) {
            int ch = i * 4 + wv;
            __builtin_amdgcn_global_load_lds((gu32*)(g + ch * 1024 + lane * 16),
                                             (lu32*)(l + ch * 1024 + lane * 16), 16, 0, 0);
        }
    }

    const int row = chunk * 64 + wv * 16 + l15;
    const unsigned short* xp = src + (size_t)row * K + lg * 8;
    short8 xf[KK];
    #pragma unroll
    for (int kk = 0; kk < KK; ++kk)
        xf[kk] = *reinterpret_cast<const short8*>(xp + kk * 32);

    float4 dr[4];
    #pragma unroll
    for (int ni = 0; ni < 4; ++ni)
        dr[ni] = *reinterpret_cast<const float4*>(&dvec[ncol0 + ni * 16 + lg * 4]);

    __syncthreads();

    f32x4 acc[4];
    #pragma unroll
    for (int ni = 0; ni < 4; ++ni) acc[ni] = (f32x4){0.f, 0.f, 0.f, 0.f};
    #pragma unroll
    for (int kk = 0; kk < KK; ++kk) {
        #pragma unroll
        for (int ni = 0; ni < 4; ++ni) {
            const int si = ((ni * 16 + l15) * K + kk * 32 + lg * 8) ^ ((l15 & 7) << 3);
            short8 wf = *reinterpret_cast<const short8*>(&Wl[si]);
            acc[ni] = __builtin_amdgcn_mfma_f32_16x16x32_bf16(wf, xf[kk], acc[ni], 0, 0, 0);
        }
    }

    const size_t rowoff = (size_t)row * C + ncol0;
    #pragma unroll
    for (int ni = 0; ni < 4; ++ni) {
        size_t off = rowoff + ni * 16 + lg * 4;
        float v0 = dr[ni].x + acc[ni][0];
        float v1 = dr[ni].y + acc[ni][1];
        float v2 = dr[ni].z + acc[ni][2];
        float v3 = dr[ni].w + acc[ni][3];
        *reinterpret_cast<uint2*>(&dec[off]) =
            make_uint2(f2bf(v0) | (f2bf(v1) << 16), f2bf(v2) | (f2bf(v3) << 16));
    }
}

// ---- gemm1: K=256, both 64-col panels staged at once; x-frags reused ----
__device__ void phase_gemm1(const MegaArgs& a, int bid, int tid, unsigned short* Wl) {
    constexpr int K = 256;
    const int lane = tid & 63;
    const int wv = tid >> 6;
    const int l15 = lane & 15, lg = lane >> 4;

    {
        const char* g = (const char*)a.Wp1;  // 64KB = both panels
        char* l = (char*)Wl;
        #pragma unroll
        for (int i = 0; i < 16; ++i) {
            int ch = i * 4 + wv;
            __builtin_amdgcn_global_load_lds((gu32*)(g + ch * 1024 + lane * 16),
                                             (lu32*)(l + ch * 1024 + lane * 16), 16, 0, 0);
        }
    }

    const int row = bid * 64 + wv * 16 + l15;
    const unsigned short* xp = a.f2p + (size_t)row * K + lg * 8;
    short8 xf[8];
    #pragma unroll
    for (int kk = 0; kk < 8; ++kk)
        xf[kk] = *reinterpret_cast<const short8*>(xp + kk * 32);

    __syncthreads();

    #pragma unroll
    for (int p = 0; p < 2; ++p) {
        const unsigned short* wb = Wl + p * 64 * K;
        f32x4 acc[4];
        #pragma unroll
        for (int ni = 0; ni < 4; ++ni) acc[ni] = (f32x4){0.f, 0.f, 0.f, 0.f};
        #pragma unroll
        for (int kk = 0; kk < 8; ++kk) {
            #pragma unroll
            for (int ni = 0; ni < 4; ++ni) {
                const int si = ((ni * 16 + l15) * K + kk * 32 + lg * 8) ^ ((l15 & 7) << 3);
                short8 wf = *reinterpret_cast<const short8*>(&wb[si]);
                acc[ni] = __builtin_amdgcn_mfma_f32_16x16x32_bf16(wf, xf[kk], acc[ni], 0, 0, 0);
            }
        }
        const int ncol0 = p * 64;
        const size_t rowoff = (size_t)row * 128 + ncol0;
        #pragma unroll
        for (int ni = 0; ni < 4; ++ni) {
            float4 dr = *reinterpret_cast<const float4*>(&a.d1[ncol0 + ni * 16 + lg * 4]);
            size_t off = rowoff + ni * 16 + lg * 4;
            float v0 = dr.x + acc[ni][0];
            float v1 = dr.y + acc[ni][1];
            float v2 = dr.z + acc[ni][2];
            float v3 = dr.w + acc[ni][3];
            *reinterpret_cast<uint2*>(&a.dec1[off]) =
                make_uint2(f2bf(v0) | (f2bf(v1) << 16), f2bf(v2) | (f2bf(v3) << 16));
        }
    }
}

// ---- gemm0: K=128, one 16KB panel, 4 row-chunks per block ----
__device__ void phase_gemm0(const MegaArgs& a, int bid, int tid, unsigned short* Wl) {
    constexpr int K = 128;
    const int lane = tid & 63;
    const int wv = tid >> 6;
    const int l15 = lane & 15, lg = lane >> 4;

    {
        const char* g = (const char*)a.Wp0;  // 16KB
        char* l = (char*)Wl;
        #pragma unroll
        for (int i = 0; i < 4; ++i) {
            int ch = i * 4 + wv;
            __builtin_amdgcn_global_load_lds((gu32*)(g + ch * 1024 + lane * 16),
                                             (lu32*)(l + ch * 1024 + lane * 16), 16, 0, 0);
        }
    }
    float4 dr[4];
    #pragma unroll
    for (int ni = 0; ni < 4; ++ni)
        dr[ni] = *reinterpret_cast<const float4*>(&a.d0[ni * 16 + lg * 4]);
    __syncthreads();

    #pragma unroll
    for (int c = 0; c < 4; ++c) {
        const int row = (bid * 4 + c) * 64 + wv * 16 + l15;
        const unsigned short* xp = a.f1p + (size_t)row * K + lg * 8;
        short8 xf[4];
        #pragma unroll
        for (int kk = 0; kk < 4; ++kk)
            xf[kk] = *reinterpret_cast<const short8*>(xp + kk * 32);
        f32x4 acc[4];
        #pragma unroll
        for (int ni = 0; ni < 4; ++ni) acc[ni] = (f32x4){0.f, 0.f, 0.f, 0.f};
        #pragma unroll
        for (int kk = 0; kk < 4; ++kk) {
            #pragma unroll
            for (int ni = 0; ni < 4; ++ni) {
                const int si = ((ni * 16 + l15) * K + kk * 32 + lg * 8) ^ ((l15 & 7) << 3);
                short8 wf = *reinterpret_cast<const short8*>(&Wl[si]);
                acc[ni] = __builtin_amdgcn_mfma_f32_16x16x32_bf16(wf, xf[kk], acc[ni], 0, 0, 0);
            }
        }
        const size_t rowoff = (size_t)row * 64;
        #pragma unroll
        for (int ni = 0; ni < 4; ++ni) {
            size_t off = rowoff + ni * 16 + lg * 4;
            float v0 = dr[ni].x + acc[ni][0];
            float v1 = dr[ni].y + acc[ni][1];
            float v2 = dr[ni].z + acc[ni][2];
            float v3 = dr[ni].w + acc[ni][3];
            *reinterpret_cast<uint2*>(&a.dec0[off]) =
                make_uint2(f2bf(v0) | (f2bf(v1) << 16), f2bf(v2) | (f2bf(v3) << 16));
        }
    }
}

// ---- batched gather-add (+ optional fused weighted stats) ----
template<int C, int IT, bool STATS, bool OUT_F32>
__device__ void ga_phase(int vb, int tid, const float* base,
                         const unsigned short* dec, const int* idx,
                         const int* cnt_next, void* outv, float* part,
                         float* aux) {
    constexpr int G = C / 8;
    constexpr int NL = 256 / G;
    const int cgi = tid % G;
    const int lr = tid / G;
    const int r0 = vb * (NL * IT);

    int g[IT];
    #pragma unroll
    for (int i = 0; i < IT; ++i) g[i] = idx[r0 + lr + NL * i];

    float wreg[IT];
    if constexpr (STATS) {
        #pragma unroll
        for (int i = 0; i < IT; ++i) wreg[i] = (float)cnt_next[r0 + lr + NL * i];
    }

    u32x4 dv[IT];
    #pragma unroll
    for (int i = 0; i < IT; ++i)
        dv[i] = *reinterpret_cast<const u32x4*>(dec + (size_t)g[i] * C + cgi * 8);

    f32x4 b0[IT], b1[IT];
    #pragma unroll
    for (int i = 0; i < IT; ++i) {
        const float* bp = base + (size_t)(r0 + lr + NL * i) * C + cgi * 8;
        b0[i] = ntload4(bp);
        b1[i] = ntload4(bp + 4);
    }

    float s[8] = {}, q[8] = {};
    #pragma unroll
    for (int i = 0; i < IT; ++i) {
        const int r = r0 + lr + NL * i;
        float v[8];
        v[0] = b0[i][0] + bf2f(dv[i][0] & 0xffffu);
        v[1] = b0[i][1] + bf2f(dv[i][0] >> 16);
        v[2] = b0[i][2] + bf2f(dv[i][1] & 0xffffu);
        v[3] = b0[i][3] + bf2f(dv[i][1] >> 16);
        v[4] = b1[i][0] + bf2f(dv[i][2] & 0xffffu);
        v[5] = b1[i][1] + bf2f(dv[i][2] >> 16);
        v[6] = b1[i][2] + bf2f(dv[i][3] & 0xffffu);
        v[7] = b1[i][3] + bf2f(dv[i][3] >> 16);
        if constexpr (OUT_F32) {
            float* op = (float*)outv + (size_t)r * C + cgi * 8;
            ntstore4(op, (f32x4){v[0], v[1], v[2], v[3]});
            ntstore4(op + 4, (f32x4){v[4], v[5], v[6], v[7]});
        } else {
            unsigned h[8];
            #pragma unroll
            for (int j = 0; j < 8; ++j) h[j] = f2bf(v[j]);
            u32x4 o = {h[0] | (h[1] << 16), h[2] | (h[3] << 16),
                       h[4] | (h[5] << 16), h[6] | (h[7] << 16)};
            *reinterpret_cast<u32x4*>((unsigned short*)outv + (size_t)r * C + cgi * 8) = o;
            if constexpr (STATS) {
                #pragma unroll
                for (int j = 0; j < 8; ++j) {
                    float rv = bf2f(h[j]);
                    s[j] += wreg[i] * rv;
                    q[j] += wreg[i] * rv * rv;
                }
            }
        }
    }

    if constexpr (STATS)
        red_write<G, NL>(aux, s, q, tid, lr, cgi, part, vb, C);
}

// ================= cooperative mega-kernel =================
__global__ __launch_bounds__(NTHR, 1) void mega(MegaArgs a) {
    __shared__ unsigned short Wl[64 * 512];  // 64 KB
    __shared__ float aux[2048];              //  8 KB
    cg::grid_group gg = cg::this_grid();
    const int bid = blockIdx.x;
    const int tid = threadIdx.x;

    phase_hist(a, bid, tid);
    __threadfence(); gg.sync(); __threadfence();

    phase_stats(a, bid, tid, aux);
    __threadfence(); gg.sync(); __threadfence();

    if (bid < 16)
        prep_phase<512, 128>(bid, tid, a.part2, a.bnw2, a.bnb2, 1.f / PN2, a.W2, a.Wp2, a.d2, aux);
    __threadfence(); gg.sync(); __threadfence();

    gemm_one<512, 256>(bid & 63, bid >> 6, tid, a.f3bf, a.Wp2, a.d2, a.dec2, Wl);
    __threadfence(); gg.sync(); __threadfence();

    ga_phase<256, 4, true, false>(bid * 2, tid, a.f2, a.dec2, a.idx0, a.cnt2, a.f2p, a.part1, aux);
    ga_phase<256, 4, true, false>(bid * 2 + 1, tid, a.f2, a.dec2, a.idx0, a.cnt2, a.f2p, a.part1, aux);
    __threadfence(); gg.sync(); __threadfence();

    if (bid < 8)
        prep_phase<256, 512>(bid, tid, a.part1, a.bnw1, a.bnb1, 1.f / PN1, a.W1, a.Wp1, a.d1, aux);
    __threadfence(); gg.sync(); __threadfence();

    phase_gemm1(a, bid, tid, Wl);
    __threadfence(); gg.sync(); __threadfence();

    ga_phase<128, 8, true, false>(bid * 2, tid, a.f1, a.dec1, a.idx1, a.cnt1, a.f1p, a.part0, aux);
    ga_phase<128, 8, true, false>(bid * 2 + 1, tid, a.f1, a.dec1, a.idx1, a.cnt1, a.f1p, a.part0, aux);
    __threadfence(); gg.sync(); __threadfence();

    if (bid < 4)
        prep_phase<128, 512>(bid, tid, a.part0, a.bnw0, a.bnb0, 1.f / PN0, a.W0, a.Wp0, a.d0, aux);
    __threadfence(); gg.sync(); __threadfence();

    phase_gemm0(a, bid, tid, Wl);
    __threadfence(); gg.sync(); __threadfence();

    #pragma unroll
    for (int c = 0; c < 4; ++c)
        ga_phase<64, 8, false, true>(bid * 4 + c, tid, a.f0, a.dec0, a.idx2, nullptr, a.out,
                                     nullptr, aux);
}

// ================= fallback kernels (same phase bodies) =================
__global__ __launch_bounds__(NTHR) void k_hist(MegaArgs a) {
    phase_hist(a, blockIdx.x, threadIdx.x);
}
__global__ __launch_bounds__(NTHR) void k_stats(MegaArgs a) {
    __shared__ float aux[2048];
    phase_stats(a, blockIdx.x, threadIdx.x, aux);
}
template<int K, int NB>
__global__ __launch_bounds__(NTHR) void k_prep(const float* part, const float* bnw,
                                               const float* bnb, float invN, const float* W,
                                               unsigned short* Wp, float* d) {
    __shared__ float aux[2048];
    prep_phase<K, NB>(blockIdx.x, threadIdx.x, part, bnw, bnb, invN, W, Wp, d, aux);
}
__global__ __launch_bounds__(NTHR) void k_gemm2(MegaArgs a) {
    __shared__ unsigned short Wl[64 * 512];
    gemm_one<512, 256>(blockIdx.x & 63, blockIdx.x >> 6, threadIdx.x, a.f3bf, a.Wp2, a.d2,
                       a.dec2, Wl);
}
__global__ __launch_bounds__(NTHR) void k_gemm1(MegaArgs a) {
    __shared__ unsigned short Wl[64 * 512];
    phase_gemm1(a, blockIdx.x, threadIdx.x, Wl);
}
__global__ __launch_bounds__(NTHR) void k_gemm0(MegaArgs a) {
    __shared__ unsigned short Wl[64 * 128];
    phase_gemm0(a, blockIdx.x, threadIdx.x, Wl);
}
__global__ __launch_bounds__(NTHR) void k_ga2(MegaArgs a) {
    __shared__ float aux[2048];
    ga_phase<256, 4, true, false>(blockIdx.x * 2, threadIdx.x, a.f2, a.dec2, a.idx0, a.cnt2,
                                  a.f2p, a.part1, aux);
    ga_phase<256, 4, true, false>(blockIdx.x * 2 + 1, threadIdx.x, a.f2, a.dec2, a.idx0, a.cnt2,
                                  a.f2p, a.part1, aux);
}
__global__ __launch_bounds__(NTHR) void k_ga1(MegaArgs a) {
    __shared__ float aux[2048];
    ga_phase<128, 8, true, false>(blockIdx.x * 2, threadIdx.x, a.f1, a.dec1, a.idx1, a.cnt1,
                                  a.f1p, a.part0, aux);
    ga_phase<128, 8, true, false>(blockIdx.x * 2 + 1, threadIdx.x, a.f1, a.dec1, a.idx1, a.cnt1,
                                  a.f1p, a.part0, aux);
}
__global__ __launch_bounds__(NTHR) void k_ga0(MegaArgs a) {
    #pragma unroll
    for (int c = 0; c < 4; ++c)
        ga_phase<64, 8, false, true>(blockIdx.x * 4 + c, threadIdx.x, a.f0, a.dec0, a.idx2,
                                     nullptr, a.out, nullptr, nullptr);
}

extern "C" void kernel_launch(void* const* d_in, const int* in_sizes, int n_in,
                              void* d_out, int out_size, void* d_ws, size_t ws_size,
                              hipStream_t stream) {
    // ---- workspace layout ----
    char* wsb = (char*)d_ws;
    unsigned short* f3bf = (unsigned short*)wsb;              // 4MB
    unsigned short* dec2 = (unsigned short*)(wsb + 4 * MB);   // 2MB
    unsigned short* dec1 = (unsigned short*)(wsb + 6 * MB);   // 4MB
    unsigned short* dec0 = (unsigned short*)(wsb + 10 * MB);  // 8MB
    unsigned short* f2p  = (unsigned short*)(wsb + 18 * MB);  // 8MB
    unsigned short* f1p  = (unsigned short*)(wsb + 26 * MB);  // 16MB
    unsigned short* Wp2  = (unsigned short*)(wsb + 42 * MB);  // 256KB
    unsigned short* Wp1  = Wp2 + 4 * 64 * 512;                // 64KB
    unsigned short* Wp0  = Wp1 + 2 * 64 * 256;                // 16KB
    int* cnt3 = (int*)(Wp0 + 64 * 128);                       // contiguous zero region
    int* cnt2 = cnt3 + PN3;
    int* cnt1 = cnt2 + PN2;
    float* part2 = (float*)(cnt1 + PN1);                      // 128*512*2
    float* part1 = part2 + 256 * 512 * 2;                     // 512*256*2
    float* part0 = part1 + 512 * 256 * 2;                     // 512*128*2
    float* d2 = part0 + 1024 * 128 * 2;
    float* d1 = d2 + 256;
    float* d0 = d1 + 128;

    MegaArgs a;
    a.f0 = (const float*)d_in[0];
    a.f1 = (const float*)d_in[1];
    a.f2 = (const float*)d_in[2];
    a.f3 = (const float*)d_in[3];
    a.bnw2 = (const float*)d_in[4];
    a.bnb2 = (const float*)d_in[5];
    a.W2 = (const float*)d_in[6];
    a.bnw1 = (const float*)d_in[7];
    a.bnb1 = (const float*)d_in[8];
    a.W1 = (const float*)d_in[9];
    a.bnw0 = (const float*)d_in[10];
    a.bnb0 = (const float*)d_in[11];
    a.W0 = (const float*)d_in[12];
    a.idx0 = (const int*)d_in[13];
    a.idx1 = (const int*)d_in[14];
    a.idx2 = (const int*)d_in[15];
    a.f3bf = f3bf; a.dec2 = dec2; a.dec1 = dec1; a.dec0 = dec0;
    a.f2p = f2p; a.f1p = f1p; a.Wp2 = Wp2; a.Wp1 = Wp1; a.Wp0 = Wp0;
    a.cnt3 = cnt3; a.cnt2 = cnt2; a.cnt1 = cnt1;
    a.part2 = part2; a.part1 = part1; a.part0 = part0;
    a.d2 = d2; a.d1 = d1; a.d0 = d0;
    a.out = (float*)d_out;

    hipMemsetAsync(cnt3, 0, (size_t)(PN3 + PN2 + PN1) * sizeof(int), stream);

    int dev = 0;
    hipGetDevice(&dev);
    int coop = 0;
    hipDeviceGetAttribute(&coop, hipDeviceAttributeCooperativeLaunch, dev);
    int maxb = 0;
    hipOccupancyMaxActiveBlocksPerMultiprocessor(&maxb, mega, NTHR, 0);

    if (coop && maxb >= 1) {
        void* kargs[] = {&a};
        hipLaunchCooperativeKernel((void*)mega, dim3(NBLK), dim3(NTHR), kargs, 0, stream);
    } else {
        k_hist<<<256, NTHR, 0, stream>>>(a);
        k_stats<<<256, NTHR, 0, stream>>>(a);
        k_prep<512, 128><<<16, NTHR, 0, stream>>>(a.part2, a.bnw2, a.bnb2, 1.f / PN2, a.W2,
                                                  a.Wp2, a.d2);
        k_gemm2<<<256, NTHR, 0, stream>>>(a);
        k_ga2<<<256, NTHR, 0, stream>>>(a);
        k_prep<256, 512><<<8, NTHR, 0, stream>>>(a.part1, a.bnw1, a.bnb1, 1.f / PN1, a.W1,
                                                 a.Wp1, a.d1);
        k_gemm1<<<256, NTHR, 0, stream>>>(a);
        k_ga1<<<256, NTHR, 0, stream>>>(a);
        k_prep<128, 512><<<4, NTHR, 0, stream>>>(a.part0, a.bnw0, a.bnb0, 1.f / PN0, a.W0,
                                                 a.Wp0, a.d0);
        k_gemm0<<<256, NTHR, 0, stream>>>(a);
        k_ga0<<<256, NTHR, 0, stream>>>(a);
    }
}